// Round 2
// baseline (589.061 us; speedup 1.0000x reference)
//
#include <hip/hip_runtime.h>

// Problem constants (fixed by the reference):
//   x:  (B=4, P=2, T=1024, F=1024) f32
//   dm: (B=4, D=16) f32
//   df: (F=1024,) f32
// Outputs (concat flat, f32):
//   dedispersed: (B, D, P, T, F) = 134,217,728 elems
//   delays:      (B, D, F)       = 65,536 elems
constexpr int Bn = 4, Pn = 2, Tn = 1024, Fn = 1024, Dn = 16;
constexpr int NCH = 8;     // F / CHUNK
constexpr int CH  = 128;   // CHUNK
constexpr long long DEDISP_ELEMS = (long long)Bn * Dn * Pn * Tn * Fn;  // 134217728

// Kernel 1: delays[b,d,f] = dm[b,d]*df[f] (f32, exact single multiply = matches ref),
// plus the 512-entry shift table s[b,d,c] = max(0, trunc(mean_{f in chunk} dm*df[f])).
// The mean is the exact sum of the f32-rounded products (double accumulator) — the
// correctly-rounded estimate of the reference's f32 pairwise mean.
__global__ __launch_bounds__(256) void prep_kernel(const float* __restrict__ dm,
                                                   const float* __restrict__ df,
                                                   float* __restrict__ delays_out,
                                                   int* __restrict__ s_ws) {
    int tid = blockIdx.x * blockDim.x + threadIdx.x;   // 0..16383
    int base = tid * 4;                                 // delays element index
    int bd = base >> 10;                                // b*D + d  (F = 1024)
    int f0 = base & 1023;
    float dmv = dm[bd];
    float4 dfv = *reinterpret_cast<const float4*>(df + f0);
    float4 o;
    o.x = dmv * dfv.x; o.y = dmv * dfv.y; o.z = dmv * dfv.z; o.w = dmv * dfv.w;
    *reinterpret_cast<float4*>(delays_out + base) = o;

    if (tid < Bn * Dn * NCH) {                          // 512 shift-table entries
        int c   = tid & (NCH - 1);
        int bd2 = tid >> 3;
        float dv = dm[bd2];
        const float* p = df + c * CH;
        double acc = 0.0;
        for (int i = 0; i < CH; ++i) {
            float prod = dv * p[i];                     // f32 round, same as ref delays
            acc += (double)prod;                        // exact sum of those f32 values
        }
        float mean = (float)(acc * 0.0078125);          // /128 exact scale, round to f32
        int s = (int)mean;                              // trunc toward zero (mean >= 0)
        if (s < 0) s = 0;
        s_ws[tid] = s;
    }
}

// Kernel 2: dedispersed[b,d,p,t,f] = x[b,p,(t+s)%T,f], float4 per lane.
// One 256-thread block-iteration covers exactly one 1024-float output row:
// reads and writes are fully coalesced 16B/lane.
__global__ __launch_bounds__(256) void gather_kernel(const float* __restrict__ x,
                                                     const int* __restrict__ s_ws,
                                                     float* __restrict__ out) {
    const long long total = DEDISP_ELEMS / 4;           // 33,554,432 float4 groups
    const long long stride = (long long)gridDim.x * blockDim.x;
    for (long long g = (long long)blockIdx.x * blockDim.x + threadIdx.x;
         g < total; g += stride) {
        int f4 = (int)(g & 255);          // float4 index within row; f = f4*4
        int t  = (int)((g >> 8) & 1023);
        int p  = (int)((g >> 18) & 1);
        int d  = (int)((g >> 19) & 15);
        int b  = (int)(g >> 23);
        int c  = f4 >> 5;                 // chunk = f/128
        int s  = s_ws[(((b << 4) + d) << 3) + c];
        int r  = t + s;
        if (r >= Tn) r -= Tn;
        int src = (((b << 1) + p) << 10 | r) << 10 | (f4 << 2);  // ((b*P+p)*T+r)*F + f
        float4 v = *reinterpret_cast<const float4*>(x + src);
        *reinterpret_cast<float4*>(out + (g << 2)) = v;
    }
}

extern "C" void kernel_launch(void* const* d_in, const int* in_sizes, int n_in,
                              void* d_out, int out_size, void* d_ws, size_t ws_size,
                              hipStream_t stream) {
    const float* x  = (const float*)d_in[0];
    const float* dm = (const float*)d_in[1];
    const float* df = (const float*)d_in[2];
    float* out = (float*)d_out;
    int* s_ws = (int*)d_ws;                    // 512 ints = 2 KB scratch

    // delays live right after the dedispersed block in d_out
    prep_kernel<<<64, 256, 0, stream>>>(dm, df, out + DEDISP_ELEMS, s_ws);
    gather_kernel<<<4096, 256, 0, stream>>>(x, s_ws, out);
}